// Round 5
// baseline (672.163 us; speedup 1.0000x reference)
//
#include <hip/hip_runtime.h>
#include <hip/hip_bf16.h>
#include <math.h>

#define B_   32
#define C_   684
#define H_   28
#define W_   112
#define L_   3136      // H_*W_
#define Q_   256
#define NP_  512
#define N_   256
#define K_   11
#define KK_  121       // K_*K_
#define KI_  684       // K rows from i
#define KPATCH_ 805    // 684 + 121 (im2col of alpha)
#define KT_  832       // padded K = 13*64
#define BM_  128       // flattened (b,l) rows per block
#define BN_  256       // p cols per block
#define KC_  64        // K chunk staged in LDS
#define NCH_ 13        // KT_/KC_

typedef short bf16x8  __attribute__((ext_vector_type(8)));
typedef float f32x16  __attribute__((ext_vector_type(16)));

// fp32 -> bf16 round-to-nearest-even (bit trick)
__device__ __forceinline__ unsigned short f2bf(float x) {
  unsigned u = __float_as_uint(x);
  u += 0x7FFF + ((u >> 16) & 1);
  return (unsigned short)(u >> 16);
}

// ---------------------------------------------------------------------------
// Kernel A: hsb[b][p] = sum_n s[b][n]*Ws[n][p] + sum_q conv_b[q]*Wf[q][p]
// ---------------------------------------------------------------------------
__global__ __launch_bounds__(256) void k_hsb(const float* __restrict__ s,
                                             const float* __restrict__ Ws,
                                             const float* __restrict__ conv_b,
                                             const float* __restrict__ Wf,
                                             float* __restrict__ hsb) {
  int b = blockIdx.x, t = threadIdx.x;
  int p0 = t, p1 = t + 256;
  float a0 = 0.f, a1 = 0.f;
  for (int n = 0; n < N_; n++) {
    float sv = s[b * N_ + n];
    a0 += sv * Ws[n * NP_ + p0];
    a1 += sv * Ws[n * NP_ + p1];
  }
  float b0 = 0.f, b1 = 0.f;
  for (int q = 0; q < Q_; q++) {
    float cb = conv_b[q];
    b0 += cb * Wf[q * NP_ + p0];
    b1 += cb * Wf[q * NP_ + p1];
  }
  hsb[b * NP_ + p0] = a0 + b0;
  hsb[b * NP_ + p1] = a1 + b1;
}

// ---------------------------------------------------------------------------
// Kernel B: w2[kykx][p] = sum_q conv_w[q][kykx] * Wf[q][p]   (fp32)
// ---------------------------------------------------------------------------
__global__ __launch_bounds__(256) void k_w2(const float* __restrict__ conv_w,
                                            const float* __restrict__ Wf,
                                            float* __restrict__ w2) {
  int kk = blockIdx.x, t = threadIdx.x;
  float a0 = 0.f, a1 = 0.f;
  for (int q = 0; q < Q_; q++) {
    float cw = conv_w[q * KK_ + kk];
    a0 += cw * Wf[q * NP_ + t];
    a1 += cw * Wf[q * NP_ + t + 256];
  }
  w2[kk * NP_ + t]       = a0;
  w2[kk * NP_ + t + 256] = a1;
}

// ---------------------------------------------------------------------------
// Kernel B2: build Wb (bf16 hi/lo, transposed, K-padded):
//   Wb[p][k] = Wa[k][p] (k<684) | w2[k-684][p] (684<=k<805) | 0
// ---------------------------------------------------------------------------
__global__ __launch_bounds__(256) void k_wb(const float* __restrict__ Wa,
                                            const float* __restrict__ w2,
                                            unsigned short* __restrict__ Wbh,
                                            unsigned short* __restrict__ Wbl) {
  __shared__ float tile[64][65];
  const int kt = blockIdx.x * 64, pt = blockIdx.y * 64;
  const int tid = threadIdx.x;
  for (int idx = tid; idx < 4096; idx += 256) {
    int r = idx >> 6, c = idx & 63;
    int k = kt + r, p = pt + c;
    float val = 0.f;
    if (k < KI_)          val = Wa[(size_t)k * NP_ + p];
    else if (k < KPATCH_) val = w2[(size_t)(k - KI_) * NP_ + p];
    tile[r][c] = val;
  }
  __syncthreads();
  for (int idx = tid; idx < 4096; idx += 256) {
    int pr = idx >> 6, ck = idx & 63;
    float x = tile[ck][pr];
    unsigned short hi = f2bf(x);
    float hif = __uint_as_float((unsigned)hi << 16);
    unsigned short lo = f2bf(x - hif);
    size_t o = (size_t)(pt + pr) * KT_ + kt + ck;
    Wbh[o] = hi;
    Wbl[o] = lo;
  }
}

// ---------------------------------------------------------------------------
// Kernel C: fused energy via MFMA (bf16 split, 3-term, fp32 accum).
// Block: 128 flattened rows (b*L+l) x 256 p, 512 threads = 8 waves (2m x 4n),
// wave owns 64 rows x 64 p => acc 2x2 f32x16 (64 AGPR).
// A (i^T | im2col(alpha) | 0) converted in-kernel, double-buffered swizzled
// LDS; B (Wb hi/lo) streamed from global (L2-resident).
// Note: 3136 % 32 == 0, so each 32-row MFMA tile lies in a single b.
// ---------------------------------------------------------------------------
__global__ __launch_bounds__(512, 3) void k_energy(const float* __restrict__ i_,
                                                   const float* __restrict__ alpha,
                                                   const unsigned short* __restrict__ Wbh,
                                                   const unsigned short* __restrict__ Wbl,
                                                   const float* __restrict__ hsb,
                                                   const float* __restrict__ v,
                                                   float* __restrict__ e_out) {
  __shared__ unsigned char As[2][2][BM_ * 128];   // [buf][hi/lo][128 rows x 128 B] = 64 KB
  __shared__ float pe[4][BM_];

  const int tid = threadIdx.x, w = tid >> 6, lane = tid & 63;
  const int wm = w >> 2, wn = w & 3;
  const int R0 = blockIdx.x * BM_;
  const int P0 = blockIdx.y * BN_;

  f32x16 acc[2][2];
#pragma unroll
  for (int mt = 0; mt < 2; mt++)
#pragma unroll
    for (int nt = 0; nt < 2; nt++)
#pragma unroll
      for (int r = 0; r < 16; r++) acc[mt][nt][r] = 0.f;

  // --- staging: thread owns flat row sr = tid&127, k-range [(tid>>7)*16,+16) ---
  const int sr = tid & 127;
  const int kq = (tid >> 7) * 16;
  const int gr = R0 + sr;
  const int sb = gr / L_, sl = gr - (gr / L_) * L_;
  const size_t ibase = (size_t)sb * ((size_t)C_ * L_) + sl;
  const int ly = sl / W_, lx = sl - (sl / W_) * W_;

  float xs[16];
  auto stage_load = [&](int ch) {
    const int kb = ch * KC_ + kq;
    if (ch < 10) {                          // all k < 684: pure-i coalesced
#pragma unroll
      for (int kk = 0; kk < 16; kk++)
        xs[kk] = i_[ibase + (size_t)(kb + kk) * L_];
    } else {
#pragma unroll
      for (int kk = 0; kk < 16; kk++) {
        int k = kb + kk;
        float t = 0.f;
        if (k < KI_) {
          t = i_[ibase + (size_t)k * L_];
        } else if (k < KPATCH_) {
          int kkp = k - KI_;
          int ky = kkp / 11, kx = kkp - ky * 11;
          int yy = ly + ky - 5, xx = lx + kx - 5;
          if (yy >= 0 && yy < H_ && xx >= 0 && xx < W_)
            t = alpha[(size_t)sb * L_ + yy * W_ + xx];
        }
        xs[kk] = t;
      }
    }
  };
  // convert + write 2 swizzled b128 per plane; slot = (k/8) ^ (row&7)
  auto stage_write = [&](int buf) {
    bf16x8 hv0, hv1, lv0, lv1;
#pragma unroll
    for (int kk = 0; kk < 8; kk++) {
      unsigned short hi = f2bf(xs[kk]);
      float hif = __uint_as_float((unsigned)hi << 16);
      hv0[kk] = (short)hi;
      lv0[kk] = (short)f2bf(xs[kk] - hif);
    }
#pragma unroll
    for (int kk = 0; kk < 8; kk++) {
      unsigned short hi = f2bf(xs[8 + kk]);
      float hif = __uint_as_float((unsigned)hi << 16);
      hv1[kk] = (short)hi;
      lv1[kk] = (short)f2bf(xs[8 + kk] - hif);
    }
    const int s0 = ((kq >> 3) ^ (sr & 7)) * 16;
    const int s1 = (((kq >> 3) + 1) ^ (sr & 7)) * 16;
    *(bf16x8*)(&As[buf][0][sr * 128 + s0]) = hv0;
    *(bf16x8*)(&As[buf][0][sr * 128 + s1]) = hv1;
    *(bf16x8*)(&As[buf][1][sr * 128 + s0]) = lv0;
    *(bf16x8*)(&As[buf][1][sr * 128 + s1]) = lv1;
  };

  stage_load(0);
  stage_write(0);
  __syncthreads();

  // compute-side indices
  const int pcol0 = P0 + wn * 64 + (lane & 31);     // nt=0 p
  const int half  = lane >> 5;
  const size_t bo0 = (size_t)pcol0 * KT_ + half * 8;
  const size_t bo1 = (size_t)(pcol0 + 32) * KT_ + half * 8;
  const int row0 = wm * 64 + (lane & 31);           // mt=0 local row
  const int row1 = row0 + 32;

  int buf = 0;
  for (int ch = 0; ch < NCH_; ch++) {
    if (ch + 1 < NCH_) stage_load(ch + 1);    // global loads in flight under MFMA

    const int kc = ch * KC_;
#pragma unroll
    for (int ks = 0; ks < 4; ks++) {
      bf16x8 bh[2], bl[2];
      const size_t ko = kc + ks * 16;
      bh[0] = *(const bf16x8*)(Wbh + bo0 + ko);
      bl[0] = *(const bf16x8*)(Wbl + bo0 + ko);
      bh[1] = *(const bf16x8*)(Wbh + bo1 + ko);
      bl[1] = *(const bf16x8*)(Wbl + bo1 + ko);
      bf16x8 ah[2], al[2];
      const int sl0 = ((ks * 2 + half) ^ (row0 & 7)) * 16;
      const int sl1 = ((ks * 2 + half) ^ (row1 & 7)) * 16;
      ah[0] = *(const bf16x8*)(&As[buf][0][row0 * 128 + sl0]);
      al[0] = *(const bf16x8*)(&As[buf][1][row0 * 128 + sl0]);
      ah[1] = *(const bf16x8*)(&As[buf][0][row1 * 128 + sl1]);
      al[1] = *(const bf16x8*)(&As[buf][1][row1 * 128 + sl1]);
#pragma unroll
      for (int mt = 0; mt < 2; mt++)
#pragma unroll
        for (int nt = 0; nt < 2; nt++) {
          acc[mt][nt] = __builtin_amdgcn_mfma_f32_32x32x16_bf16(ah[mt], bh[nt], acc[mt][nt], 0, 0, 0);
          acc[mt][nt] = __builtin_amdgcn_mfma_f32_32x32x16_bf16(ah[mt], bl[nt], acc[mt][nt], 0, 0, 0);
          acc[mt][nt] = __builtin_amdgcn_mfma_f32_32x32x16_bf16(al[mt], bh[nt], acc[mt][nt], 0, 0, 0);
        }
    }

    if (ch + 1 < NCH_) {
      stage_write(buf ^ 1);                   // convert + LDS write after MFMA
      __syncthreads();
      buf ^= 1;
    }
  }

  // epilogue: pre = acc + hsb[b(row)][p]; partial e over this wave's 64 p.
  // Each 32-row tile lies in one b (3136 % 32 == 0).
  const float vv0 = v[pcol0], vv1 = v[pcol0 + 32];
#pragma unroll
  for (int mt = 0; mt < 2; mt++) {
    const int bmt = (R0 + wm * 64 + mt * 32) / L_;
    const float h0 = hsb[bmt * NP_ + pcol0];
    const float h1 = hsb[bmt * NP_ + pcol0 + 32];
#pragma unroll
    for (int r = 0; r < 16; r++) {
      float val = vv0 * tanhf(acc[mt][0][r] + h0) + vv1 * tanhf(acc[mt][1][r] + h1);
      val += __shfl_xor(val, 16);
      val += __shfl_xor(val, 8);
      val += __shfl_xor(val, 4);
      val += __shfl_xor(val, 2);
      val += __shfl_xor(val, 1);
      if ((lane & 31) == 0) {
        int rl = wm * 64 + mt * 32 + (r & 3) + 8 * (r >> 2) + 4 * half;
        pe[wn][rl] = val;
      }
    }
  }
  __syncthreads();
  if (tid < BM_) {
    float s = pe[0][tid] + pe[1][tid] + pe[2][tid] + pe[3][tid];
    if (blockIdx.y == 0)
      e_out[(size_t)(R0 + tid)] = s;
    else
      e_out[(size_t)L_ * B_ + (R0 + tid)] = s;   // partial for p-half 1
  }
}

// ---------------------------------------------------------------------------
// Kernel D: softmax over L per batch (sums the two p-half partials of e).
// ---------------------------------------------------------------------------
__global__ __launch_bounds__(256) void k_softmax(const float* __restrict__ e,
                                                 float* __restrict__ w) {
  __shared__ float sh[L_];
  __shared__ float red[4];
  const int b = blockIdx.x, tid = threadIdx.x;
  const int lane = tid & 63, wv = tid >> 6;

  float m = -1e30f;
  for (int idx = tid; idx < L_; idx += 256) {
    float t = e[(size_t)b * L_ + idx] + e[(size_t)L_ * B_ + (size_t)b * L_ + idx];
    sh[idx] = t;
    m = fmaxf(m, t);
  }
  m = fmaxf(m, __shfl_down(m, 32));
  m = fmaxf(m, __shfl_down(m, 16));
  m = fmaxf(m, __shfl_down(m, 8));
  m = fmaxf(m, __shfl_down(m, 4));
  m = fmaxf(m, __shfl_down(m, 2));
  m = fmaxf(m, __shfl_down(m, 1));
  if (lane == 0) red[wv] = m;
  __syncthreads();
  m = fmaxf(fmaxf(red[0], red[1]), fmaxf(red[2], red[3]));
  __syncthreads();

  float s = 0.f;
  for (int idx = tid; idx < L_; idx += 256) {
    float t = expf(sh[idx] - m);
    sh[idx] = t;
    s += t;
  }
  s += __shfl_down(s, 32);
  s += __shfl_down(s, 16);
  s += __shfl_down(s, 8);
  s += __shfl_down(s, 4);
  s += __shfl_down(s, 2);
  s += __shfl_down(s, 1);
  if (lane == 0) red[wv] = s;
  __syncthreads();
  float total = red[0] + red[1] + red[2] + red[3];
  float inv = 1.f / total;
  for (int idx = tid; idx < L_; idx += 256)
    w[(size_t)b * L_ + idx] = sh[idx] * inv;
}

// ---------------------------------------------------------------------------
// Kernel E: context c_At[b][c] = sum_l w[b][l] * i[b][c][l]  (memory-bound)
// ---------------------------------------------------------------------------
__global__ __launch_bounds__(256) void k_context(const float* __restrict__ i_,
                                                 const float* __restrict__ w,
                                                 float* __restrict__ out) {
  __shared__ float red[4];
  const int b = blockIdx.y, c = blockIdx.x, tid = threadIdx.x;
  const int lane = tid & 63, wv = tid >> 6;
  const float4* row = (const float4*)(i_ + ((size_t)b * C_ + c) * L_);
  const float4* wr  = (const float4*)(w + (size_t)b * L_);
  float s = 0.f;
  for (int idx = tid; idx < L_ / 4; idx += 256) {
    float4 a = row[idx];
    float4 ww = wr[idx];
    s += a.x * ww.x + a.y * ww.y + a.z * ww.z + a.w * ww.w;
  }
  s += __shfl_down(s, 32);
  s += __shfl_down(s, 16);
  s += __shfl_down(s, 8);
  s += __shfl_down(s, 4);
  s += __shfl_down(s, 2);
  s += __shfl_down(s, 1);
  if (lane == 0) red[wv] = s;
  __syncthreads();
  if (tid == 0) out[(size_t)b * C_ + c] = red[0] + red[1] + red[2] + red[3];
}

// ---------------------------------------------------------------------------
extern "C" void kernel_launch(void* const* d_in, const int* in_sizes, int n_in,
                              void* d_out, int out_size, void* d_ws, size_t ws_size,
                              hipStream_t stream) {
  const float* i_      = (const float*)d_in[0];
  const float* hat_s_t = (const float*)d_in[1];
  const float* alpha   = (const float*)d_in[2];
  const float* conv_w  = (const float*)d_in[3];
  const float* conv_b  = (const float*)d_in[4];
  const float* Wa      = (const float*)d_in[5];
  const float* Wf      = (const float*)d_in[6];
  const float* Ws      = (const float*)d_in[7];
  const float* v       = (const float*)d_in[8];
  float* out = (float*)d_out;

  float* ws   = (float*)d_ws;
  float* hsb  = ws;                               // 32*512     f
  float* w2   = hsb + B_ * NP_;                   // 121*512    f
  float* e    = w2 + KK_ * NP_;                   // 2*32*3136  f (two p-half partials)
  float* anew = e + 2 * B_ * L_;                  // 32*3136    f
  unsigned short* Wbh = (unsigned short*)(anew + B_ * L_);  // 512*832 u16
  unsigned short* Wbl = Wbh + (size_t)NP_ * KT_;            // 512*832 u16
  // total ~3.2 MB workspace

  k_hsb<<<dim3(B_), dim3(256), 0, stream>>>(hat_s_t, Ws, conv_b, Wf, hsb);
  k_w2<<<dim3(KK_), dim3(256), 0, stream>>>(conv_w, Wf, w2);
  k_wb<<<dim3(NCH_, 8), dim3(256), 0, stream>>>(Wa, w2, Wbh, Wbl);
  k_energy<<<dim3((B_ * L_) / BM_, NP_ / BN_), dim3(512), 0, stream>>>(i_, alpha, Wbh, Wbl, hsb, v, e);
  k_softmax<<<dim3(B_), dim3(256), 0, stream>>>(e, anew);
  k_context<<<dim3(C_, B_), dim3(256), 0, stream>>>(i_, anew, out);
}

// Round 6
// 492.498 us; speedup vs baseline: 1.3648x; 1.3648x over previous
//
#include <hip/hip_runtime.h>
#include <hip/hip_bf16.h>
#include <math.h>

#define B_   32
#define C_   684
#define H_   28
#define W_   112
#define L_   3136      // H_*W_
#define Q_   256
#define NP_  512
#define N_   256
#define K_   11
#define KK_  121       // K_*K_
#define KI_  684       // K rows from i
#define KPATCH_ 805    // 684 + 121 (im2col of alpha)
#define KT_  832       // padded K = 13*64
#define KTILES_ 52     // KT_/16
#define BM_  64        // l rows per block (64 | L_, so block lies in one b)
#define KC_  64        // K chunk staged in LDS
#define NCH_ 13        // KT_/KC_

typedef short bf16x8  __attribute__((ext_vector_type(8)));
typedef short bf16x4  __attribute__((ext_vector_type(4)));
typedef float f32x16  __attribute__((ext_vector_type(16)));

// fp32 -> bf16 round-to-nearest-even (bit trick)
__device__ __forceinline__ unsigned short f2bf(float x) {
  unsigned u = __float_as_uint(x);
  u += 0x7FFF + ((u >> 16) & 1);
  return (unsigned short)(u >> 16);
}

// ---------------------------------------------------------------------------
// Kernel A: hsb[b][p] = sum_n s[b][n]*Ws[n][p] + sum_q conv_b[q]*Wf[q][p]
// ---------------------------------------------------------------------------
__global__ __launch_bounds__(256) void k_hsb(const float* __restrict__ s,
                                             const float* __restrict__ Ws,
                                             const float* __restrict__ conv_b,
                                             const float* __restrict__ Wf,
                                             float* __restrict__ hsb) {
  int b = blockIdx.x, t = threadIdx.x;
  int p0 = t, p1 = t + 256;
  float a0 = 0.f, a1 = 0.f;
  for (int n = 0; n < N_; n++) {
    float sv = s[b * N_ + n];
    a0 += sv * Ws[n * NP_ + p0];
    a1 += sv * Ws[n * NP_ + p1];
  }
  float b0 = 0.f, b1 = 0.f;
  for (int q = 0; q < Q_; q++) {
    float cb = conv_b[q];
    b0 += cb * Wf[q * NP_ + p0];
    b1 += cb * Wf[q * NP_ + p1];
  }
  hsb[b * NP_ + p0] = a0 + b0;
  hsb[b * NP_ + p1] = a1 + b1;
}

// ---------------------------------------------------------------------------
// Kernel B: w2[kykx][p] = sum_q conv_w[q][kykx] * Wf[q][p]   (fp32)
// ---------------------------------------------------------------------------
__global__ __launch_bounds__(256) void k_w2(const float* __restrict__ conv_w,
                                            const float* __restrict__ Wf,
                                            float* __restrict__ w2) {
  int kk = blockIdx.x, t = threadIdx.x;
  float a0 = 0.f, a1 = 0.f;
  for (int q = 0; q < Q_; q++) {
    float cw = conv_w[q * KK_ + kk];
    a0 += cw * Wf[q * NP_ + t];
    a1 += cw * Wf[q * NP_ + t + 256];
  }
  w2[kk * NP_ + t]       = a0;
  w2[kk * NP_ + t + 256] = a1;
}

// ---------------------------------------------------------------------------
// Kernel B2: build frag-packed Wb (bf16 hi/lo):
//   logical Wb[k][p] = Wa[k][p] (k<684) | w2[k-684][p] (684<=k<805) | 0
// packed so a wave's MFMA B-frag (ptile,ktile) is lane-contiguous 1KB:
//   Wbp[(ptile*52+ktile)*1024 + lane*8 + kidx]        (hi plane)
//   Wbp[(ptile*52+ktile)*1024 + 512 + lane*8 + kidx]  (lo plane)
// where lane = (p&31) + ((k>>3)&1)*32, kidx = k&7.
// ---------------------------------------------------------------------------
__global__ __launch_bounds__(512) void k_wb(const float* __restrict__ Wa,
                                            const float* __restrict__ w2,
                                            unsigned short* __restrict__ Wbp) {
  const int k = blockIdx.x;          // 0..831
  const int p = threadIdx.x;         // 0..511
  float val = 0.f;
  if (k < KI_)          val = Wa[(size_t)k * NP_ + p];
  else if (k < KPATCH_) val = w2[(size_t)(k - KI_) * NP_ + p];
  unsigned short hi = f2bf(val);
  float hif = __uint_as_float((unsigned)hi << 16);
  unsigned short lo = f2bf(val - hif);
  const int ptile = p >> 5, ktile = k >> 4;
  const int lane = (p & 31) + (((k >> 3) & 1) << 5);
  const int kidx = k & 7;
  const size_t base = ((size_t)(ptile * KTILES_ + ktile)) * 1024 + lane * 8 + kidx;
  Wbp[base]       = hi;
  Wbp[base + 512] = lo;
}

// ---------------------------------------------------------------------------
// Kernel C: fused energy via MFMA (bf16 split, 3-term, fp32 accum).
// 1024 threads = 16 waves (2m x 8n); block tile 64 l x 512 p (full NP);
// wave tile 32 l x 64 p -> acc = 2 x f32x16 = 32 AGPR. Target: total regs
// <= 128 -> 4 waves/SIMD. A (i^T|im2col(alpha)|0) converted in-kernel into
// swizzled dbuf LDS; B read as coalesced frag-packed 1KB loads (L2-resident).
// ---------------------------------------------------------------------------
__global__ __launch_bounds__(1024, 4) void k_energy(const float* __restrict__ i_,
                                                    const float* __restrict__ alpha,
                                                    const unsigned short* __restrict__ Wbp,
                                                    const float* __restrict__ hsb,
                                                    const float* __restrict__ v,
                                                    float* __restrict__ e_out) {
  __shared__ __attribute__((aligned(16))) unsigned char As[2][2][BM_ * 128]; // 32 KB
  __shared__ float pe[8][BM_];

  const int tid = threadIdx.x, w = tid >> 6, lane = tid & 63;
  const int wm = w >> 3, wn = w & 7;           // 2m x 8n
  const int R0 = blockIdx.x * BM_;
  const int bb = R0 / L_;                      // whole block in one b (64 | L_)
  const int l0 = R0 - bb * L_;

  f32x16 acc[2];
#pragma unroll
  for (int nt = 0; nt < 2; nt++)
#pragma unroll
    for (int r = 0; r < 16; r++) acc[nt][r] = 0.f;

  // --- staging: thread owns row sr = tid&63, k-group kq = (tid>>6)*4 ---
  const int sr = tid & 63;
  const int kq = (tid >> 6) * 4;               // 0,4,...,60
  const int sl = l0 + sr;
  const size_t ibase = (size_t)bb * ((size_t)C_ * L_) + sl;
  const int ly = sl / W_, lx = sl - ly * W_;

  float xs[4];
  auto stage_load = [&](int ch) {
    const int kb = ch * KC_ + kq;
    if (ch < 10) {                             // all k < 640: pure-i coalesced
#pragma unroll
      for (int j = 0; j < 4; j++)
        xs[j] = i_[ibase + (size_t)(kb + j) * L_];
    } else {
#pragma unroll
      for (int j = 0; j < 4; j++) {
        int k = kb + j;
        float t = 0.f;
        if (k < KI_) {
          t = i_[ibase + (size_t)k * L_];
        } else if (k < KPATCH_) {
          int kkp = k - KI_;
          int ky = kkp / 11, kx = kkp - ky * 11;
          int yy = ly + ky - 5, xx = lx + kx - 5;
          if (yy >= 0 && yy < H_ && xx >= 0 && xx < W_)
            t = alpha[(size_t)bb * L_ + yy * W_ + xx];
        }
        xs[j] = t;
      }
    }
  };
  // convert + one swizzled ds_write_b64 per plane; slot16 = kq>>3 (+8B if kq&4)
  auto stage_write = [&](int buf) {
    bf16x4 hv, lv;
#pragma unroll
    for (int j = 0; j < 4; j++) {
      unsigned short hi = f2bf(xs[j]);
      float hif = __uint_as_float((unsigned)hi << 16);
      hv[j] = (short)hi;
      lv[j] = (short)f2bf(xs[j] - hif);
    }
    const int byte = sr * 128 + (((kq >> 3) ^ (sr & 7)) << 4) + ((kq & 4) << 1);
    *(bf16x4*)(&As[buf][0][byte]) = hv;
    *(bf16x4*)(&As[buf][1][byte]) = lv;
  };

  stage_load(0);
  stage_write(0);
  __syncthreads();

  // compute-side indices
  const int col = lane & 31, half = lane >> 5;
  const int arow = wm * 32 + col;              // LDS A row
  const int abase = arow * 128;
  const int aswz = arow & 7;
  const unsigned short* wb0 = Wbp + ((size_t)(wn * 2 + 0) * KTILES_) * 1024 + lane * 8;
  const unsigned short* wb1 = Wbp + ((size_t)(wn * 2 + 1) * KTILES_) * 1024 + lane * 8;

  int buf = 0;
  for (int ch = 0; ch < NCH_; ch++) {
    if (ch + 1 < NCH_) stage_load(ch + 1);     // next-chunk global loads in flight

#pragma unroll
    for (int ks = 0; ks < 4; ks++) {
      const int kt = ch * 4 + ks;
      bf16x8 bh0 = *(const bf16x8*)(wb0 + (size_t)kt * 1024);
      bf16x8 bl0 = *(const bf16x8*)(wb0 + (size_t)kt * 1024 + 512);
      bf16x8 bh1 = *(const bf16x8*)(wb1 + (size_t)kt * 1024);
      bf16x8 bl1 = *(const bf16x8*)(wb1 + (size_t)kt * 1024 + 512);
      const int aoff = abase + (((ks * 2 + half) ^ aswz) << 4);
      bf16x8 ah = *(const bf16x8*)(&As[buf][0][aoff]);
      bf16x8 al = *(const bf16x8*)(&As[buf][1][aoff]);
      acc[0] = __builtin_amdgcn_mfma_f32_32x32x16_bf16(ah, bh0, acc[0], 0, 0, 0);
      acc[0] = __builtin_amdgcn_mfma_f32_32x32x16_bf16(ah, bl0, acc[0], 0, 0, 0);
      acc[0] = __builtin_amdgcn_mfma_f32_32x32x16_bf16(al, bh0, acc[0], 0, 0, 0);
      acc[1] = __builtin_amdgcn_mfma_f32_32x32x16_bf16(ah, bh1, acc[1], 0, 0, 0);
      acc[1] = __builtin_amdgcn_mfma_f32_32x32x16_bf16(ah, bl1, acc[1], 0, 0, 0);
      acc[1] = __builtin_amdgcn_mfma_f32_32x32x16_bf16(al, bh1, acc[1], 0, 0, 0);
    }

    if (ch + 1 < NCH_) {
      stage_write(buf ^ 1);                    // convert + LDS write after MFMA
      __syncthreads();
      buf ^= 1;
    }
  }

  // epilogue: pre = acc + hsb[bb][p]; e partial over this wave's 64 p
  const int p0 = wn * 64 + col, p1 = p0 + 32;
  const float h0 = hsb[bb * NP_ + p0], h1 = hsb[bb * NP_ + p1];
  const float v0 = v[p0], v1 = v[p1];
#pragma unroll
  for (int r = 0; r < 16; r++) {
    float val = v0 * tanhf(acc[0][r] + h0) + v1 * tanhf(acc[1][r] + h1);
    val += __shfl_xor(val, 16);
    val += __shfl_xor(val, 8);
    val += __shfl_xor(val, 4);
    val += __shfl_xor(val, 2);
    val += __shfl_xor(val, 1);
    if (col == 0) {
      int row = wm * 32 + (r & 3) + 8 * (r >> 2) + 4 * half;
      pe[wn][row] = val;
    }
  }
  __syncthreads();
  if (tid < BM_) {
    float s = 0.f;
#pragma unroll
    for (int ww = 0; ww < 8; ww++) s += pe[ww][tid];
    e_out[(size_t)(R0 + tid)] = s;
  }
}

// ---------------------------------------------------------------------------
// Kernel D: softmax over L per batch.
// ---------------------------------------------------------------------------
__global__ __launch_bounds__(256) void k_softmax(const float* __restrict__ e,
                                                 float* __restrict__ w) {
  __shared__ float sh[L_];
  __shared__ float red[4];
  const int b = blockIdx.x, tid = threadIdx.x;
  const int lane = tid & 63, wv = tid >> 6;

  float m = -1e30f;
  for (int idx = tid; idx < L_; idx += 256) {
    float t = e[(size_t)b * L_ + idx];
    sh[idx] = t;
    m = fmaxf(m, t);
  }
  m = fmaxf(m, __shfl_down(m, 32));
  m = fmaxf(m, __shfl_down(m, 16));
  m = fmaxf(m, __shfl_down(m, 8));
  m = fmaxf(m, __shfl_down(m, 4));
  m = fmaxf(m, __shfl_down(m, 2));
  m = fmaxf(m, __shfl_down(m, 1));
  if (lane == 0) red[wv] = m;
  __syncthreads();
  m = fmaxf(fmaxf(red[0], red[1]), fmaxf(red[2], red[3]));
  __syncthreads();

  float s = 0.f;
  for (int idx = tid; idx < L_; idx += 256) {
    float t = expf(sh[idx] - m);
    sh[idx] = t;
    s += t;
  }
  s += __shfl_down(s, 32);
  s += __shfl_down(s, 16);
  s += __shfl_down(s, 8);
  s += __shfl_down(s, 4);
  s += __shfl_down(s, 2);
  s += __shfl_down(s, 1);
  if (lane == 0) red[wv] = s;
  __syncthreads();
  float total = red[0] + red[1] + red[2] + red[3];
  float inv = 1.f / total;
  for (int idx = tid; idx < L_; idx += 256)
    w[(size_t)b * L_ + idx] = sh[idx] * inv;
}

// ---------------------------------------------------------------------------
// Kernel E: context c_At[b][c] = sum_l w[b][l] * i[b][c][l]  (memory-bound)
// ---------------------------------------------------------------------------
__global__ __launch_bounds__(256) void k_context(const float* __restrict__ i_,
                                                 const float* __restrict__ w,
                                                 float* __restrict__ out) {
  __shared__ float red[4];
  const int b = blockIdx.y, c = blockIdx.x, tid = threadIdx.x;
  const int lane = tid & 63, wv = tid >> 6;
  const float4* row = (const float4*)(i_ + ((size_t)b * C_ + c) * L_);
  const float4* wr  = (const float4*)(w + (size_t)b * L_);
  float s = 0.f;
  for (int idx = tid; idx < L_ / 4; idx += 256) {
    float4 a = row[idx];
    float4 ww = wr[idx];
    s += a.x * ww.x + a.y * ww.y + a.z * ww.z + a.w * ww.w;
  }
  s += __shfl_down(s, 32);
  s += __shfl_down(s, 16);
  s += __shfl_down(s, 8);
  s += __shfl_down(s, 4);
  s += __shfl_down(s, 2);
  s += __shfl_down(s, 1);
  if (lane == 0) red[wv] = s;
  __syncthreads();
  if (tid == 0) out[(size_t)b * C_ + c] = red[0] + red[1] + red[2] + red[3];
}

// ---------------------------------------------------------------------------
extern "C" void kernel_launch(void* const* d_in, const int* in_sizes, int n_in,
                              void* d_out, int out_size, void* d_ws, size_t ws_size,
                              hipStream_t stream) {
  const float* i_      = (const float*)d_in[0];
  const float* hat_s_t = (const float*)d_in[1];
  const float* alpha   = (const float*)d_in[2];
  const float* conv_w  = (const float*)d_in[3];
  const float* conv_b  = (const float*)d_in[4];
  const float* Wa      = (const float*)d_in[5];
  const float* Wf      = (const float*)d_in[6];
  const float* Ws      = (const float*)d_in[7];
  const float* v       = (const float*)d_in[8];
  float* out = (float*)d_out;

  float* ws   = (float*)d_ws;
  float* hsb  = ws;                               // 32*512    f
  float* w2   = hsb + B_ * NP_;                   // 121*512   f
  float* e    = w2 + KK_ * NP_;                   // 32*3136   f
  float* anew = e + B_ * L_;                      // 32*3136   f
  unsigned short* Wbp = (unsigned short*)(anew + B_ * L_);  // 16*52*1024 u16 = 1.7 MB
  // total ~2.8 MB workspace

  k_hsb<<<dim3(B_), dim3(256), 0, stream>>>(hat_s_t, Ws, conv_b, Wf, hsb);
  k_w2<<<dim3(KK_), dim3(256), 0, stream>>>(conv_w, Wf, w2);
  k_wb<<<dim3(KT_), dim3(512), 0, stream>>>(Wa, w2, Wbp);
  k_energy<<<dim3((B_ * L_) / BM_), dim3(1024), 0, stream>>>(i_, alpha, Wbp, hsb, v, e);
  k_softmax<<<dim3(B_), dim3(256), 0, stream>>>(e, anew);
  k_context<<<dim3(C_, B_), dim3(256), 0, stream>>>(i_, anew, out);
}

// Round 9
// 445.979 us; speedup vs baseline: 1.5072x; 1.1043x over previous
//
#include <hip/hip_runtime.h>
#include <hip/hip_bf16.h>
#include <math.h>

#define B_   32
#define C_   684
#define H_   28
#define W_   112
#define L_   3136      // H_*W_
#define Q_   256
#define NP_  512
#define N_   256
#define K_   11
#define KK_  121       // K_*K_
#define KI_  684       // K rows from i
#define KPATCH_ 805    // 684 + 121 (im2col of alpha)
#define KT_  832       // padded K = 13*64
#define KTILES_ 52     // KT_/16
#define BM_  32        // l rows per block (32 | L_, so block lies in one b)
#define KC_  64        // K chunk staged in LDS
#define NCH_ 13        // KT_/KC_

typedef short bf16x8  __attribute__((ext_vector_type(8)));
typedef short bf16x4  __attribute__((ext_vector_type(4)));
typedef float f32x16  __attribute__((ext_vector_type(16)));

#define MFMA32(a, b, c) __builtin_amdgcn_mfma_f32_32x32x16_bf16((a), (b), (c), 0, 0, 0)

// fp32 -> bf16 round-to-nearest-even (bit trick)
__device__ __forceinline__ unsigned short f2bf(float x) {
  unsigned u = __float_as_uint(x);
  u += 0x7FFF + ((u >> 16) & 1);
  return (unsigned short)(u >> 16);
}

// ---------------------------------------------------------------------------
// Kernel A: hsb[b][p] = sum_n s[b][n]*Ws[n][p] + sum_q conv_b[q]*Wf[q][p]
// ---------------------------------------------------------------------------
__global__ __launch_bounds__(256) void k_hsb(const float* __restrict__ s,
                                             const float* __restrict__ Ws,
                                             const float* __restrict__ conv_b,
                                             const float* __restrict__ Wf,
                                             float* __restrict__ hsb) {
  int b = blockIdx.x, t = threadIdx.x;
  int p0 = t, p1 = t + 256;
  float a0 = 0.f, a1 = 0.f;
  for (int n = 0; n < N_; n++) {
    float sv = s[b * N_ + n];
    a0 += sv * Ws[n * NP_ + p0];
    a1 += sv * Ws[n * NP_ + p1];
  }
  float b0 = 0.f, b1 = 0.f;
  for (int q = 0; q < Q_; q++) {
    float cb = conv_b[q];
    b0 += cb * Wf[q * NP_ + p0];
    b1 += cb * Wf[q * NP_ + p1];
  }
  hsb[b * NP_ + p0] = a0 + b0;
  hsb[b * NP_ + p1] = a1 + b1;
}

// ---------------------------------------------------------------------------
// Kernel B: w2[kykx][p] = sum_q conv_w[q][kykx] * Wf[q][p]   (fp32)
// ---------------------------------------------------------------------------
__global__ __launch_bounds__(256) void k_w2(const float* __restrict__ conv_w,
                                            const float* __restrict__ Wf,
                                            float* __restrict__ w2) {
  int kk = blockIdx.x, t = threadIdx.x;
  float a0 = 0.f, a1 = 0.f;
  for (int q = 0; q < Q_; q++) {
    float cw = conv_w[q * KK_ + kk];
    a0 += cw * Wf[q * NP_ + t];
    a1 += cw * Wf[q * NP_ + t + 256];
  }
  w2[kk * NP_ + t]       = a0;
  w2[kk * NP_ + t + 256] = a1;
}

// ---------------------------------------------------------------------------
// Kernel B2: build frag-packed Wb (bf16 hi/lo):
//   logical Wb[k][p] = Wa[k][p] (k<684) | w2[k-684][p] (684<=k<805) | 0
// packed so a wave's MFMA B-frag (ptile,ktile) is lane-contiguous 1KB:
//   Wbp[(ptile*52+ktile)*1024 + lane*8 + kidx]        (hi plane)
//   Wbp[(ptile*52+ktile)*1024 + 512 + lane*8 + kidx]  (lo plane)
// where lane = (p&31) + ((k>>3)&1)*32, kidx = k&7.
// ---------------------------------------------------------------------------
__global__ __launch_bounds__(512) void k_wb(const float* __restrict__ Wa,
                                            const float* __restrict__ w2,
                                            unsigned short* __restrict__ Wbp) {
  const int k = blockIdx.x;          // 0..831
  const int p = threadIdx.x;         // 0..511
  float val = 0.f;
  if (k < KI_)          val = Wa[(size_t)k * NP_ + p];
  else if (k < KPATCH_) val = w2[(size_t)(k - KI_) * NP_ + p];
  unsigned short hi = f2bf(val);
  float hif = __uint_as_float((unsigned)hi << 16);
  unsigned short lo = f2bf(val - hif);
  const int ptile = p >> 5, ktile = k >> 4;
  const int lane = (p & 31) + (((k >> 3) & 1) << 5);
  const int kidx = k & 7;
  const size_t base = ((size_t)(ptile * KTILES_ + ktile)) * 1024 + lane * 8 + kidx;
  Wbp[base]       = hi;
  Wbp[base + 512] = lo;
}

// ---------------------------------------------------------------------------
// Kernel C: fused energy via MFMA (bf16 split, 3-term, fp32 accum).
// R9 = R6's PROVEN pipeline (load-next -> MFMA -> write-next -> syncthreads,
// no setprio, no raw barriers), retiled: 512 threads = 8 waves, block tile
// 32 l x 512 p (full NP, no e-partials); wave tile 32 l x 64 p ->
// acc = 2 x f32x16 (32 AGPR). ~84 unified regs -> 3 blocks/CU so one block's
// barrier drain hides under another block's MFMA phase.
// ---------------------------------------------------------------------------
__global__ __launch_bounds__(512, 4) void k_energy(const float* __restrict__ i_,
                                                   const float* __restrict__ alpha,
                                                   const unsigned short* __restrict__ Wbp,
                                                   const float* __restrict__ hsb,
                                                   const float* __restrict__ v,
                                                   float* __restrict__ e_out) {
  __shared__ __attribute__((aligned(16))) unsigned char As[2][2][BM_ * 128]; // 16 KB
  __shared__ float pe[8][BM_];

  const int tid = threadIdx.x, w = tid >> 6, lane = tid & 63;
  const int R0 = blockIdx.x * BM_;
  const int bb = R0 / L_;                      // whole block in one b (32 | L_)
  const int l0 = R0 - bb * L_;

  f32x16 acc[2];
#pragma unroll
  for (int nt = 0; nt < 2; nt++)
#pragma unroll
    for (int r = 0; r < 16; r++) acc[nt][r] = 0.f;

  // --- staging: thread owns row sr = tid&31, k-group kq = (tid>>5)*4 ---
  const int sr = tid & 31;
  const int kq = (tid >> 5) * 4;               // 0,4,...,60
  const int sl = l0 + sr;
  const size_t ibase = (size_t)bb * ((size_t)C_ * L_) + sl;
  const int ly = sl / W_, lx = sl - ly * W_;

  float xs[4];
  auto stage_load = [&](int ch) {
    const int kb = ch * KC_ + kq;
    if (ch < 10) {                             // all k < 640: pure-i coalesced
#pragma unroll
      for (int j = 0; j < 4; j++)
        xs[j] = i_[ibase + (size_t)(kb + j) * L_];
    } else {
#pragma unroll
      for (int j = 0; j < 4; j++) {
        int k = kb + j;
        float t = 0.f;
        if (k < KI_) {
          t = i_[ibase + (size_t)k * L_];
        } else if (k < KPATCH_) {
          int kkp = k - KI_;
          int ky = kkp / 11, kx = kkp - ky * 11;
          int yy = ly + ky - 5, xx = lx + kx - 5;
          if (yy >= 0 && yy < H_ && xx >= 0 && xx < W_)
            t = alpha[(size_t)bb * L_ + yy * W_ + xx];
        }
        xs[j] = t;
      }
    }
  };
  // convert + one swizzled ds_write_b64 per plane; slot16 = kq>>3 (+8B if kq&4)
  auto stage_write = [&](int buf) {
    bf16x4 hv, lv;
#pragma unroll
    for (int j = 0; j < 4; j++) {
      unsigned short hi = f2bf(xs[j]);
      float hif = __uint_as_float((unsigned)hi << 16);
      hv[j] = (short)hi;
      lv[j] = (short)f2bf(xs[j] - hif);
    }
    const int byte = sr * 128 + (((kq >> 3) ^ (sr & 7)) << 4) + ((kq & 4) << 1);
    *(bf16x4*)(&As[buf][0][byte]) = hv;
    *(bf16x4*)(&As[buf][1][byte]) = lv;
  };

  // prologue (R6 order)
  stage_load(0);
  stage_write(0);
  __syncthreads();

  // compute-side indices
  const int col = lane & 31, half = lane >> 5;
  const int abase = col * 128;                 // A row = col (32-row tile)
  const int aswz = col & 7;
  const unsigned short* wb0 = Wbp + ((size_t)(w * 2 + 0) * KTILES_) * 1024 + lane * 8;
  const unsigned short* wb1 = Wbp + ((size_t)(w * 2 + 1) * KTILES_) * 1024 + lane * 8;

  int buf = 0;
  for (int ch = 0; ch < NCH_; ch++) {
    if (ch + 1 < NCH_) stage_load(ch + 1);     // next-chunk loads in flight

#pragma unroll
    for (int ks = 0; ks < 4; ks++) {
      const size_t o = (size_t)(ch * 4 + ks) * 1024;
      bf16x8 bh0 = *(const bf16x8*)(wb0 + o);
      bf16x8 bl0 = *(const bf16x8*)(wb0 + o + 512);
      bf16x8 bh1 = *(const bf16x8*)(wb1 + o);
      bf16x8 bl1 = *(const bf16x8*)(wb1 + o + 512);
      const int aoff = abase + (((ks * 2 + half) ^ aswz) << 4);
      bf16x8 ah = *(const bf16x8*)(&As[buf][0][aoff]);
      bf16x8 al = *(const bf16x8*)(&As[buf][1][aoff]);
      acc[0] = MFMA32(ah, bh0, acc[0]);
      acc[0] = MFMA32(ah, bl0, acc[0]);
      acc[0] = MFMA32(al, bh0, acc[0]);
      acc[1] = MFMA32(ah, bh1, acc[1]);
      acc[1] = MFMA32(ah, bl1, acc[1]);
      acc[1] = MFMA32(al, bh1, acc[1]);
    }

    if (ch + 1 < NCH_) {
      stage_write(buf ^ 1);                    // convert + LDS write after MFMA
      __syncthreads();
      buf ^= 1;
    }
  }

  // epilogue: pre = acc + hsb[bb][p]; e partial over this wave's 64 p
  const int p0 = w * 64 + col, p1 = p0 + 32;
  const float h0 = hsb[bb * NP_ + p0], h1 = hsb[bb * NP_ + p1];
  const float v0 = v[p0], v1 = v[p1];
#pragma unroll
  for (int r = 0; r < 16; r++) {
    float val = v0 * tanhf(acc[0][r] + h0) + v1 * tanhf(acc[1][r] + h1);
    val += __shfl_xor(val, 16);
    val += __shfl_xor(val, 8);
    val += __shfl_xor(val, 4);
    val += __shfl_xor(val, 2);
    val += __shfl_xor(val, 1);
    if (col == 0) {
      int row = (r & 3) + 8 * (r >> 2) + 4 * half;
      pe[w][row] = val;
    }
  }
  __syncthreads();
  if (tid < BM_) {
    float s = 0.f;
#pragma unroll
    for (int ww = 0; ww < 8; ww++) s += pe[ww][tid];
    e_out[(size_t)(R0 + tid)] = s;
  }
}

// ---------------------------------------------------------------------------
// Kernel D: softmax over L per batch.
// ---------------------------------------------------------------------------
__global__ __launch_bounds__(256) void k_softmax(const float* __restrict__ e,
                                                 float* __restrict__ w) {
  __shared__ float sh[L_];
  __shared__ float red[4];
  const int b = blockIdx.x, tid = threadIdx.x;
  const int lane = tid & 63, wv = tid >> 6;

  float m = -1e30f;
  for (int idx = tid; idx < L_; idx += 256) {
    float t = e[(size_t)b * L_ + idx];
    sh[idx] = t;
    m = fmaxf(m, t);
  }
  m = fmaxf(m, __shfl_down(m, 32));
  m = fmaxf(m, __shfl_down(m, 16));
  m = fmaxf(m, __shfl_down(m, 8));
  m = fmaxf(m, __shfl_down(m, 4));
  m = fmaxf(m, __shfl_down(m, 2));
  m = fmaxf(m, __shfl_down(m, 1));
  if (lane == 0) red[wv] = m;
  __syncthreads();
  m = fmaxf(fmaxf(red[0], red[1]), fmaxf(red[2], red[3]));
  __syncthreads();

  float s = 0.f;
  for (int idx = tid; idx < L_; idx += 256) {
    float t = expf(sh[idx] - m);
    sh[idx] = t;
    s += t;
  }
  s += __shfl_down(s, 32);
  s += __shfl_down(s, 16);
  s += __shfl_down(s, 8);
  s += __shfl_down(s, 4);
  s += __shfl_down(s, 2);
  s += __shfl_down(s, 1);
  if (lane == 0) red[wv] = s;
  __syncthreads();
  float total = red[0] + red[1] + red[2] + red[3];
  float inv = 1.f / total;
  for (int idx = tid; idx < L_; idx += 256)
    w[(size_t)b * L_ + idx] = sh[idx] * inv;
}

// ---------------------------------------------------------------------------
// Kernel E: context c_At[b][c] = sum_l w[b][l] * i[b][c][l]  (memory-bound)
// ---------------------------------------------------------------------------
__global__ __launch_bounds__(256) void k_context(const float* __restrict__ i_,
                                                 const float* __restrict__ w,
                                                 float* __restrict__ out) {
  __shared__ float red[4];
  const int b = blockIdx.y, c = blockIdx.x, tid = threadIdx.x;
  const int lane = tid & 63, wv = tid >> 6;
  const float4* row = (const float4*)(i_ + ((size_t)b * C_ + c) * L_);
  const float4* wr  = (const float4*)(w + (size_t)b * L_);
  float s = 0.f;
  for (int idx = tid; idx < L_ / 4; idx += 256) {
    float4 a = row[idx];
    float4 ww = wr[idx];
    s += a.x * ww.x + a.y * ww.y + a.z * ww.z + a.w * ww.w;
  }
  s += __shfl_down(s, 32);
  s += __shfl_down(s, 16);
  s += __shfl_down(s, 8);
  s += __shfl_down(s, 4);
  s += __shfl_down(s, 2);
  s += __shfl_down(s, 1);
  if (lane == 0) red[wv] = s;
  __syncthreads();
  if (tid == 0) out[(size_t)b * C_ + c] = red[0] + red[1] + red[2] + red[3];
}

// ---------------------------------------------------------------------------
extern "C" void kernel_launch(void* const* d_in, const int* in_sizes, int n_in,
                              void* d_out, int out_size, void* d_ws, size_t ws_size,
                              hipStream_t stream) {
  const float* i_      = (const float*)d_in[0];
  const float* hat_s_t = (const float*)d_in[1];
  const float* alpha   = (const float*)d_in[2];
  const float* conv_w  = (const float*)d_in[3];
  const float* conv_b  = (const float*)d_in[4];
  const float* Wa      = (const float*)d_in[5];
  const float* Wf      = (const float*)d_in[6];
  const float* Ws      = (const float*)d_in[7];
  const float* v       = (const float*)d_in[8];
  float* out = (float*)d_out;

  float* ws   = (float*)d_ws;
  float* hsb  = ws;                               // 32*512    f
  float* w2   = hsb + B_ * NP_;                   // 121*512   f
  float* e    = w2 + KK_ * NP_;                   // 32*3136   f
  float* anew = e + B_ * L_;                      // 32*3136   f
  unsigned short* Wbp = (unsigned short*)(anew + B_ * L_);  // 16*52*1024 u16 = 1.7 MB
  // total ~2.8 MB workspace

  k_hsb<<<dim3(B_), dim3(256), 0, stream>>>(hat_s_t, Ws, conv_b, Wf, hsb);
  k_w2<<<dim3(KK_), dim3(256), 0, stream>>>(conv_w, Wf, w2);
  k_wb<<<dim3(KT_), dim3(512), 0, stream>>>(Wa, w2, Wbp);
  k_energy<<<dim3((B_ * L_) / BM_), dim3(512), 0, stream>>>(i_, alpha, Wbp, hsb, v, e);
  k_softmax<<<dim3(B_), dim3(256), 0, stream>>>(e, anew);
  k_context<<<dim3(C_, B_), dim3(256), 0, stream>>>(i_, anew, out);
}

// Round 10
// 424.418 us; speedup vs baseline: 1.5837x; 1.0508x over previous
//
#include <hip/hip_runtime.h>
#include <hip/hip_bf16.h>
#include <math.h>

#define B_   32
#define C_   684
#define H_   28
#define W_   112
#define L_   3136      // H_*W_
#define Q_   256
#define NP_  512
#define N_   256
#define K_   11
#define KK_  121       // K_*K_
#define KI_  684       // K rows from i
#define KPATCH_ 805    // 684 + 121 (im2col of alpha)
#define KT_  832       // padded K = 13*64
#define KTILES_ 52     // KT_/16
#define BM_  32        // l rows per block (32 | L_, so block lies in one b)
#define KC_  64        // K chunk staged in LDS
#define NCH_ 13        // KT_/KC_

typedef short bf16x8  __attribute__((ext_vector_type(8)));
typedef short bf16x4  __attribute__((ext_vector_type(4)));
typedef float f32x16  __attribute__((ext_vector_type(16)));

#define MFMA32(a, b, c) __builtin_amdgcn_mfma_f32_32x32x16_bf16((a), (b), (c), 0, 0, 0)

// fp32 -> bf16 round-to-nearest-even (bit trick)
__device__ __forceinline__ unsigned short f2bf(float x) {
  unsigned u = __float_as_uint(x);
  u += 0x7FFF + ((u >> 16) & 1);
  return (unsigned short)(u >> 16);
}

// ---------------------------------------------------------------------------
// Kernel A: hsb[b][p] = sum_n s[b][n]*Ws[n][p] + sum_q conv_b[q]*Wf[q][p]
// ---------------------------------------------------------------------------
__global__ __launch_bounds__(256) void k_hsb(const float* __restrict__ s,
                                             const float* __restrict__ Ws,
                                             const float* __restrict__ conv_b,
                                             const float* __restrict__ Wf,
                                             float* __restrict__ hsb) {
  int b = blockIdx.x, t = threadIdx.x;
  int p0 = t, p1 = t + 256;
  float a0 = 0.f, a1 = 0.f;
  for (int n = 0; n < N_; n++) {
    float sv = s[b * N_ + n];
    a0 += sv * Ws[n * NP_ + p0];
    a1 += sv * Ws[n * NP_ + p1];
  }
  float b0 = 0.f, b1 = 0.f;
  for (int q = 0; q < Q_; q++) {
    float cb = conv_b[q];
    b0 += cb * Wf[q * NP_ + p0];
    b1 += cb * Wf[q * NP_ + p1];
  }
  hsb[b * NP_ + p0] = a0 + b0;
  hsb[b * NP_ + p1] = a1 + b1;
}

// ---------------------------------------------------------------------------
// Kernel B: w2[kykx][p] = sum_q conv_w[q][kykx] * Wf[q][p]   (fp32)
// ---------------------------------------------------------------------------
__global__ __launch_bounds__(256) void k_w2(const float* __restrict__ conv_w,
                                            const float* __restrict__ Wf,
                                            float* __restrict__ w2) {
  int kk = blockIdx.x, t = threadIdx.x;
  float a0 = 0.f, a1 = 0.f;
  for (int q = 0; q < Q_; q++) {
    float cw = conv_w[q * KK_ + kk];
    a0 += cw * Wf[q * NP_ + t];
    a1 += cw * Wf[q * NP_ + t + 256];
  }
  w2[kk * NP_ + t]       = a0;
  w2[kk * NP_ + t + 256] = a1;
}

// ---------------------------------------------------------------------------
// Kernel B2: build frag-packed Wb (bf16 hi/lo):
//   logical Wb[k][p] = Wa[k][p] (k<684) | w2[k-684][p] (684<=k<805) | 0
// packed so a wave's MFMA B-frag (ptile,ktile) is lane-contiguous 1KB:
//   Wbp[(ptile*52+ktile)*1024 + lane*8 + kidx]        (hi plane)
//   Wbp[(ptile*52+ktile)*1024 + 512 + lane*8 + kidx]  (lo plane)
// where lane = (p&31) + ((k>>3)&1)*32, kidx = k&7.
// ---------------------------------------------------------------------------
__global__ __launch_bounds__(512) void k_wb(const float* __restrict__ Wa,
                                            const float* __restrict__ w2,
                                            unsigned short* __restrict__ Wbp) {
  const int k = blockIdx.x;          // 0..831
  const int p = threadIdx.x;         // 0..511
  float val = 0.f;
  if (k < KI_)          val = Wa[(size_t)k * NP_ + p];
  else if (k < KPATCH_) val = w2[(size_t)(k - KI_) * NP_ + p];
  unsigned short hi = f2bf(val);
  float hif = __uint_as_float((unsigned)hi << 16);
  unsigned short lo = f2bf(val - hif);
  const int ptile = p >> 5, ktile = k >> 4;
  const int lane = (p & 31) + (((k >> 3) & 1) << 5);
  const int kidx = k & 7;
  const size_t base = ((size_t)(ptile * KTILES_ + ktile)) * 1024 + lane * 8 + kidx;
  Wbp[base]       = hi;
  Wbp[base + 512] = lo;
}

// ---------------------------------------------------------------------------
// Kernel C: fused energy via MFMA (bf16 split, 3-term, fp32 accum).
// R10 = R9's PROVEN pipeline (load-next -> MFMA -> write-next -> syncthreads)
// with ONE surgical register-only change: B-fragment software pipeline one
// ks-step ahead, carried across chunk boundaries (the ks=3 preload crosses
// the barrier in registers), + setprio around the MFMA cluster.
// 512 threads = 8 waves, block tile 32 l x 512 p; wave tile 32 l x 64 p ->
// acc = 2 x f32x16 (32 AGPR).
// ---------------------------------------------------------------------------
__global__ __launch_bounds__(512, 4) void k_energy(const float* __restrict__ i_,
                                                   const float* __restrict__ alpha,
                                                   const unsigned short* __restrict__ Wbp,
                                                   const float* __restrict__ hsb,
                                                   const float* __restrict__ v,
                                                   float* __restrict__ e_out) {
  __shared__ __attribute__((aligned(16))) unsigned char As[2][2][BM_ * 128]; // 16 KB
  __shared__ float pe[8][BM_];

  const int tid = threadIdx.x, w = tid >> 6, lane = tid & 63;
  const int R0 = blockIdx.x * BM_;
  const int bb = R0 / L_;                      // whole block in one b (32 | L_)
  const int l0 = R0 - bb * L_;

  f32x16 acc[2];
#pragma unroll
  for (int nt = 0; nt < 2; nt++)
#pragma unroll
    for (int r = 0; r < 16; r++) acc[nt][r] = 0.f;

  // --- staging: thread owns row sr = tid&31, k-group kq = (tid>>5)*4 ---
  const int sr = tid & 31;
  const int kq = (tid >> 5) * 4;               // 0,4,...,60
  const int sl = l0 + sr;
  const size_t ibase = (size_t)bb * ((size_t)C_ * L_) + sl;
  const int ly = sl / W_, lx = sl - ly * W_;

  float xs[4];
  auto stage_load = [&](int ch) {
    const int kb = ch * KC_ + kq;
    if (ch < 10) {                             // all k < 640: pure-i coalesced
#pragma unroll
      for (int j = 0; j < 4; j++)
        xs[j] = i_[ibase + (size_t)(kb + j) * L_];
    } else {
#pragma unroll
      for (int j = 0; j < 4; j++) {
        int k = kb + j;
        float t = 0.f;
        if (k < KI_) {
          t = i_[ibase + (size_t)k * L_];
        } else if (k < KPATCH_) {
          int kkp = k - KI_;
          int ky = kkp / 11, kx = kkp - ky * 11;
          int yy = ly + ky - 5, xx = lx + kx - 5;
          if (yy >= 0 && yy < H_ && xx >= 0 && xx < W_)
            t = alpha[(size_t)bb * L_ + yy * W_ + xx];
        }
        xs[j] = t;
      }
    }
  };
  // convert + one swizzled ds_write_b64 per plane; slot16 = kq>>3 (+8B if kq&4)
  auto stage_write = [&](int buf) {
    bf16x4 hv, lv;
#pragma unroll
    for (int j = 0; j < 4; j++) {
      unsigned short hi = f2bf(xs[j]);
      float hif = __uint_as_float((unsigned)hi << 16);
      hv[j] = (short)hi;
      lv[j] = (short)f2bf(xs[j] - hif);
    }
    const int byte = sr * 128 + (((kq >> 3) ^ (sr & 7)) << 4) + ((kq & 4) << 1);
    *(bf16x4*)(&As[buf][0][byte]) = hv;
    *(bf16x4*)(&As[buf][1][byte]) = lv;
  };

  // prologue (R9 order)
  stage_load(0);
  stage_write(0);
  __syncthreads();

  // compute-side indices
  const int col = lane & 31, half = lane >> 5;
  const int abase = col * 128;                 // A row = col (32-row tile)
  const int aswz = col & 7;
  const unsigned short* wb0 = Wbp + ((size_t)(w * 2 + 0) * KTILES_) * 1024 + lane * 8;
  const unsigned short* wb1 = Wbp + ((size_t)(w * 2 + 1) * KTILES_) * 1024 + lane * 8;

  // B-pipeline prologue: preload ktile 0 fragments
  bf16x8 cbh0 = *(const bf16x8*)(wb0);
  bf16x8 cbl0 = *(const bf16x8*)(wb0 + 512);
  bf16x8 cbh1 = *(const bf16x8*)(wb1);
  bf16x8 cbl1 = *(const bf16x8*)(wb1 + 512);

  int buf = 0;
  for (int ch = 0; ch < NCH_; ch++) {
    if (ch + 1 < NCH_) stage_load(ch + 1);     // next-chunk A loads in flight

#pragma unroll
    for (int ks = 0; ks < 4; ks++) {
      const int g = ch * 4 + ks;
      bf16x8 nbh0, nbl0, nbh1, nbl1;
      if (g + 1 < KTILES_) {                   // issue next B frags pre-MFMA
        const size_t o = (size_t)(g + 1) * 1024;
        nbh0 = *(const bf16x8*)(wb0 + o);
        nbl0 = *(const bf16x8*)(wb0 + o + 512);
        nbh1 = *(const bf16x8*)(wb1 + o);
        nbl1 = *(const bf16x8*)(wb1 + o + 512);
      }
      const int aoff = abase + (((ks * 2 + half) ^ aswz) << 4);
      bf16x8 ah = *(const bf16x8*)(&As[buf][0][aoff]);
      bf16x8 al = *(const bf16x8*)(&As[buf][1][aoff]);
      __builtin_amdgcn_s_setprio(1);
      acc[0] = MFMA32(ah, cbh0, acc[0]);
      acc[0] = MFMA32(ah, cbl0, acc[0]);
      acc[0] = MFMA32(al, cbh0, acc[0]);
      acc[1] = MFMA32(ah, cbh1, acc[1]);
      acc[1] = MFMA32(ah, cbl1, acc[1]);
      acc[1] = MFMA32(al, cbh1, acc[1]);
      __builtin_amdgcn_s_setprio(0);
      if (g + 1 < KTILES_) {
        cbh0 = nbh0; cbl0 = nbl0; cbh1 = nbh1; cbl1 = nbl1;
      }
    }

    if (ch + 1 < NCH_) {
      stage_write(buf ^ 1);                    // convert + LDS write after MFMA
      __syncthreads();
      buf ^= 1;
    }
  }

  // epilogue: pre = acc + hsb[bb][p]; e partial over this wave's 64 p
  const int p0 = w * 64 + col, p1 = p0 + 32;
  const float h0 = hsb[bb * NP_ + p0], h1 = hsb[bb * NP_ + p1];
  const float v0 = v[p0], v1 = v[p1];
#pragma unroll
  for (int r = 0; r < 16; r++) {
    float val = v0 * tanhf(acc[0][r] + h0) + v1 * tanhf(acc[1][r] + h1);
    val += __shfl_xor(val, 16);
    val += __shfl_xor(val, 8);
    val += __shfl_xor(val, 4);
    val += __shfl_xor(val, 2);
    val += __shfl_xor(val, 1);
    if (col == 0) {
      int row = (r & 3) + 8 * (r >> 2) + 4 * half;
      pe[w][row] = val;
    }
  }
  __syncthreads();
  if (tid < BM_) {
    float s = 0.f;
#pragma unroll
    for (int ww = 0; ww < 8; ww++) s += pe[ww][tid];
    e_out[(size_t)(R0 + tid)] = s;
  }
}

// ---------------------------------------------------------------------------
// Kernel D: softmax over L per batch.
// ---------------------------------------------------------------------------
__global__ __launch_bounds__(256) void k_softmax(const float* __restrict__ e,
                                                 float* __restrict__ w) {
  __shared__ float sh[L_];
  __shared__ float red[4];
  const int b = blockIdx.x, tid = threadIdx.x;
  const int lane = tid & 63, wv = tid >> 6;

  float m = -1e30f;
  for (int idx = tid; idx < L_; idx += 256) {
    float t = e[(size_t)b * L_ + idx];
    sh[idx] = t;
    m = fmaxf(m, t);
  }
  m = fmaxf(m, __shfl_down(m, 32));
  m = fmaxf(m, __shfl_down(m, 16));
  m = fmaxf(m, __shfl_down(m, 8));
  m = fmaxf(m, __shfl_down(m, 4));
  m = fmaxf(m, __shfl_down(m, 2));
  m = fmaxf(m, __shfl_down(m, 1));
  if (lane == 0) red[wv] = m;
  __syncthreads();
  m = fmaxf(fmaxf(red[0], red[1]), fmaxf(red[2], red[3]));
  __syncthreads();

  float s = 0.f;
  for (int idx = tid; idx < L_; idx += 256) {
    float t = expf(sh[idx] - m);
    sh[idx] = t;
    s += t;
  }
  s += __shfl_down(s, 32);
  s += __shfl_down(s, 16);
  s += __shfl_down(s, 8);
  s += __shfl_down(s, 4);
  s += __shfl_down(s, 2);
  s += __shfl_down(s, 1);
  if (lane == 0) red[wv] = s;
  __syncthreads();
  float total = red[0] + red[1] + red[2] + red[3];
  float inv = 1.f / total;
  for (int idx = tid; idx < L_; idx += 256)
    w[(size_t)b * L_ + idx] = sh[idx] * inv;
}

// ---------------------------------------------------------------------------
// Kernel E: context c_At[b][c] = sum_l w[b][l] * i[b][c][l]  (memory-bound)
// ---------------------------------------------------------------------------
__global__ __launch_bounds__(256) void k_context(const float* __restrict__ i_,
                                                 const float* __restrict__ w,
                                                 float* __restrict__ out) {
  __shared__ float red[4];
  const int b = blockIdx.y, c = blockIdx.x, tid = threadIdx.x;
  const int lane = tid & 63, wv = tid >> 6;
  const float4* row = (const float4*)(i_ + ((size_t)b * C_ + c) * L_);
  const float4* wr  = (const float4*)(w + (size_t)b * L_);
  float s = 0.f;
  for (int idx = tid; idx < L_ / 4; idx += 256) {
    float4 a = row[idx];
    float4 ww = wr[idx];
    s += a.x * ww.x + a.y * ww.y + a.z * ww.z + a.w * ww.w;
  }
  s += __shfl_down(s, 32);
  s += __shfl_down(s, 16);
  s += __shfl_down(s, 8);
  s += __shfl_down(s, 4);
  s += __shfl_down(s, 2);
  s += __shfl_down(s, 1);
  if (lane == 0) red[wv] = s;
  __syncthreads();
  if (tid == 0) out[(size_t)b * C_ + c] = red[0] + red[1] + red[2] + red[3];
}

// ---------------------------------------------------------------------------
extern "C" void kernel_launch(void* const* d_in, const int* in_sizes, int n_in,
                              void* d_out, int out_size, void* d_ws, size_t ws_size,
                              hipStream_t stream) {
  const float* i_      = (const float*)d_in[0];
  const float* hat_s_t = (const float*)d_in[1];
  const float* alpha   = (const float*)d_in[2];
  const float* conv_w  = (const float*)d_in[3];
  const float* conv_b  = (const float*)d_in[4];
  const float* Wa      = (const float*)d_in[5];
  const float* Wf      = (const float*)d_in[6];
  const float* Ws      = (const float*)d_in[7];
  const float* v       = (const float*)d_in[8];
  float* out = (float*)d_out;

  float* ws   = (float*)d_ws;
  float* hsb  = ws;                               // 32*512    f
  float* w2   = hsb + B_ * NP_;                   // 121*512   f
  float* e    = w2 + KK_ * NP_;                   // 32*3136   f
  float* anew = e + B_ * L_;                      // 32*3136   f
  unsigned short* Wbp = (unsigned short*)(anew + B_ * L_);  // 16*52*1024 u16 = 1.7 MB
  // total ~2.8 MB workspace

  k_hsb<<<dim3(B_), dim3(256), 0, stream>>>(hat_s_t, Ws, conv_b, Wf, hsb);
  k_w2<<<dim3(KK_), dim3(256), 0, stream>>>(conv_w, Wf, w2);
  k_wb<<<dim3(KT_), dim3(512), 0, stream>>>(Wa, w2, Wbp);
  k_energy<<<dim3((B_ * L_) / BM_), dim3(512), 0, stream>>>(i_, alpha, Wbp, hsb, v, e);
  k_softmax<<<dim3(B_), dim3(256), 0, stream>>>(e, anew);
  k_context<<<dim3(C_, B_), dim3(256), 0, stream>>>(i_, anew, out);
}

// Round 13
// 376.572 us; speedup vs baseline: 1.7850x; 1.1271x over previous
//
#include <hip/hip_runtime.h>
#include <hip/hip_bf16.h>
#include <math.h>

#define B_   32
#define C_   684
#define H_   28
#define W_   112
#define L_   3136      // H_*W_
#define Q_   256
#define NP_  512
#define N_   256
#define K_   11
#define KK_  121       // K_*K_
#define KI_  684       // K rows from i
#define KPATCH_ 805    // 684 + 121 (im2col of alpha)
#define KT_  832       // padded K = 13*64
#define KTILES_ 52     // KT_/16
#define BM_  32        // l rows per block (32 | L_, so block lies in one b)
#define KC_  64        // K chunk staged in LDS
#define NCH_ 13        // KT_/KC_

typedef short bf16x8  __attribute__((ext_vector_type(8)));
typedef short bf16x4  __attribute__((ext_vector_type(4)));
typedef float f32x16  __attribute__((ext_vector_type(16)));

#define MFMA32(a, b, c) __builtin_amdgcn_mfma_f32_32x32x16_bf16((a), (b), (c), 0, 0, 0)

// fp32 -> bf16 round-to-nearest-even (bit trick)
__device__ __forceinline__ unsigned short f2bf(float x) {
  unsigned u = __float_as_uint(x);
  u += 0x7FFF + ((u >> 16) & 1);
  return (unsigned short)(u >> 16);
}

// ---------------------------------------------------------------------------
// Kernel A: hsb[b][p] = sum_n s[b][n]*Ws[n][p] + sum_q conv_b[q]*Wf[q][p]
// ---------------------------------------------------------------------------
__global__ __launch_bounds__(256) void k_hsb(const float* __restrict__ s,
                                             const float* __restrict__ Ws,
                                             const float* __restrict__ conv_b,
                                             const float* __restrict__ Wf,
                                             float* __restrict__ hsb) {
  int b = blockIdx.x, t = threadIdx.x;
  int p0 = t, p1 = t + 256;
  float a0 = 0.f, a1 = 0.f;
  for (int n = 0; n < N_; n++) {
    float sv = s[b * N_ + n];
    a0 += sv * Ws[n * NP_ + p0];
    a1 += sv * Ws[n * NP_ + p1];
  }
  float b0 = 0.f, b1 = 0.f;
  for (int q = 0; q < Q_; q++) {
    float cb = conv_b[q];
    b0 += cb * Wf[q * NP_ + p0];
    b1 += cb * Wf[q * NP_ + p1];
  }
  hsb[b * NP_ + p0] = a0 + b0;
  hsb[b * NP_ + p1] = a1 + b1;
}

// ---------------------------------------------------------------------------
// Kernel B: w2[kykx][p] = sum_q conv_w[q][kykx] * Wf[q][p]   (fp32)
// ---------------------------------------------------------------------------
__global__ __launch_bounds__(256) void k_w2(const float* __restrict__ conv_w,
                                            const float* __restrict__ Wf,
                                            float* __restrict__ w2) {
  int kk = blockIdx.x, t = threadIdx.x;
  float a0 = 0.f, a1 = 0.f;
  for (int q = 0; q < Q_; q++) {
    float cw = conv_w[q * KK_ + kk];
    a0 += cw * Wf[q * NP_ + t];
    a1 += cw * Wf[q * NP_ + t + 256];
  }
  w2[kk * NP_ + t]       = a0;
  w2[kk * NP_ + t + 256] = a1;
}

// ---------------------------------------------------------------------------
// Kernel B2: build frag-packed Wb (bf16 hi/lo):
//   logical Wb[k][p] = Wa[k][p] (k<684) | w2[k-684][p] (684<=k<805) | 0
// packed so a wave's MFMA B-frag (ptile,ktile) is lane-contiguous 1KB:
//   Wbp[(ptile*52+ktile)*1024 + lane*8 + kidx]        (hi plane)
//   Wbp[(ptile*52+ktile)*1024 + 512 + lane*8 + kidx]  (lo plane)
// where lane = (p&31) + ((k>>3)&1)*32, kidx = k&7.
// ---------------------------------------------------------------------------
__global__ __launch_bounds__(512) void k_wb(const float* __restrict__ Wa,
                                            const float* __restrict__ w2,
                                            unsigned short* __restrict__ Wbp) {
  const int k = blockIdx.x;          // 0..831
  const int p = threadIdx.x;         // 0..511
  float val = 0.f;
  if (k < KI_)          val = Wa[(size_t)k * NP_ + p];
  else if (k < KPATCH_) val = w2[(size_t)(k - KI_) * NP_ + p];
  unsigned short hi = f2bf(val);
  float hif = __uint_as_float((unsigned)hi << 16);
  unsigned short lo = f2bf(val - hif);
  const int ptile = p >> 5, ktile = k >> 4;
  const int lane = (p & 31) + (((k >> 3) & 1) << 5);
  const int kidx = k & 7;
  const size_t base = ((size_t)(ptile * KTILES_ + ktile)) * 1024 + lane * 8 + kidx;
  Wbp[base]       = hi;
  Wbp[base + 512] = lo;
}

// ---------------------------------------------------------------------------
// Kernel C: fused energy via MFMA (bf16 2-term split: ah*(bh+bl), fp32 accum).
// R11 = R10's PROVEN pipeline with the A-lo plane removed: A staged as plain
// bf16 (rne), B keeps hi+lo correction. Error = A-rounding only
// (~1e-3 on pre, ~5e-4 on output; threshold 2.3e-3).
// 512 threads = 8 waves, block tile 32 l x 512 p; wave tile 32 l x 64 p ->
// acc = 2 x f32x16 (32 AGPR). 4 MFMA per ks (was 6).
// ---------------------------------------------------------------------------
__global__ __launch_bounds__(512, 4) void k_energy(const float* __restrict__ i_,
                                                   const float* __restrict__ alpha,
                                                   const unsigned short* __restrict__ Wbp,
                                                   const float* __restrict__ hsb,
                                                   const float* __restrict__ v,
                                                   float* __restrict__ e_out) {
  __shared__ __attribute__((aligned(16))) unsigned char As[2][BM_ * 128]; // 8 KB
  __shared__ float pe[8][BM_];

  const int tid = threadIdx.x, w = tid >> 6, lane = tid & 63;
  const int R0 = blockIdx.x * BM_;
  const int bb = R0 / L_;                      // whole block in one b (32 | L_)
  const int l0 = R0 - bb * L_;

  f32x16 acc[2];
#pragma unroll
  for (int nt = 0; nt < 2; nt++)
#pragma unroll
    for (int r = 0; r < 16; r++) acc[nt][r] = 0.f;

  // --- staging: thread owns row sr = tid&31, k-group kq = (tid>>5)*4 ---
  const int sr = tid & 31;
  const int kq = (tid >> 5) * 4;               // 0,4,...,60
  const int sl = l0 + sr;
  const size_t ibase = (size_t)bb * ((size_t)C_ * L_) + sl;
  const int ly = sl / W_, lx = sl - ly * W_;

  float xs[4];
  auto stage_load = [&](int ch) {
    const int kb = ch * KC_ + kq;
    if (ch < 10) {                             // all k < 640: pure-i coalesced
#pragma unroll
      for (int j = 0; j < 4; j++)
        xs[j] = i_[ibase + (size_t)(kb + j) * L_];
    } else {
#pragma unroll
      for (int j = 0; j < 4; j++) {
        int k = kb + j;
        float t = 0.f;
        if (k < KI_) {
          t = i_[ibase + (size_t)k * L_];
        } else if (k < KPATCH_) {
          int kkp = k - KI_;
          int ky = kkp / 11, kx = kkp - ky * 11;
          int yy = ly + ky - 5, xx = lx + kx - 5;
          if (yy >= 0 && yy < H_ && xx >= 0 && xx < W_)
            t = alpha[(size_t)bb * L_ + yy * W_ + xx];
        }
        xs[j] = t;
      }
    }
  };
  // convert (hi only) + one swizzled ds_write_b64; slot16 = kq>>3 (+8B if kq&4)
  auto stage_write = [&](int buf) {
    bf16x4 hv;
#pragma unroll
    for (int j = 0; j < 4; j++) hv[j] = (short)f2bf(xs[j]);
    const int byte = sr * 128 + (((kq >> 3) ^ (sr & 7)) << 4) + ((kq & 4) << 1);
    *(bf16x4*)(&As[buf][byte]) = hv;
  };

  // prologue (R9/R10 order)
  stage_load(0);
  stage_write(0);
  __syncthreads();

  // compute-side indices
  const int col = lane & 31, half = lane >> 5;
  const int abase = col * 128;                 // A row = col (32-row tile)
  const int aswz = col & 7;
  const unsigned short* wb0 = Wbp + ((size_t)(w * 2 + 0) * KTILES_) * 1024 + lane * 8;
  const unsigned short* wb1 = Wbp + ((size_t)(w * 2 + 1) * KTILES_) * 1024 + lane * 8;

  // B-pipeline prologue: preload ktile 0 fragments
  bf16x8 cbh0 = *(const bf16x8*)(wb0);
  bf16x8 cbl0 = *(const bf16x8*)(wb0 + 512);
  bf16x8 cbh1 = *(const bf16x8*)(wb1);
  bf16x8 cbl1 = *(const bf16x8*)(wb1 + 512);

  int buf = 0;
  for (int ch = 0; ch < NCH_; ch++) {
    if (ch + 1 < NCH_) stage_load(ch + 1);     // next-chunk A loads in flight

#pragma unroll
    for (int ks = 0; ks < 4; ks++) {
      const int g = ch * 4 + ks;
      bf16x8 nbh0, nbl0, nbh1, nbl1;
      if (g + 1 < KTILES_) {                   // issue next B frags pre-MFMA
        const size_t o = (size_t)(g + 1) * 1024;
        nbh0 = *(const bf16x8*)(wb0 + o);
        nbl0 = *(const bf16x8*)(wb0 + o + 512);
        nbh1 = *(const bf16x8*)(wb1 + o);
        nbl1 = *(const bf16x8*)(wb1 + o + 512);
      }
      const int aoff = abase + (((ks * 2 + half) ^ aswz) << 4);
      bf16x8 ah = *(const bf16x8*)(&As[buf][aoff]);
      __builtin_amdgcn_s_setprio(1);
      acc[0] = MFMA32(ah, cbh0, acc[0]);
      acc[0] = MFMA32(ah, cbl0, acc[0]);
      acc[1] = MFMA32(ah, cbh1, acc[1]);
      acc[1] = MFMA32(ah, cbl1, acc[1]);
      __builtin_amdgcn_s_setprio(0);
      if (g + 1 < KTILES_) {
        cbh0 = nbh0; cbl0 = nbl0; cbh1 = nbh1; cbl1 = nbl1;
      }
    }

    if (ch + 1 < NCH_) {
      stage_write(buf ^ 1);                    // convert + LDS write after MFMA
      __syncthreads();
      buf ^= 1;
    }
  }

  // epilogue: pre = acc + hsb[bb][p]; e partial over this wave's 64 p
  const int p0 = w * 64 + col, p1 = p0 + 32;
  const float h0 = hsb[bb * NP_ + p0], h1 = hsb[bb * NP_ + p1];
  const float v0 = v[p0], v1 = v[p1];
#pragma unroll
  for (int r = 0; r < 16; r++) {
    float val = v0 * tanhf(acc[0][r] + h0) + v1 * tanhf(acc[1][r] + h1);
    val += __shfl_xor(val, 16);
    val += __shfl_xor(val, 8);
    val += __shfl_xor(val, 4);
    val += __shfl_xor(val, 2);
    val += __shfl_xor(val, 1);
    if (col == 0) {
      int row = (r & 3) + 8 * (r >> 2) + 4 * half;
      pe[w][row] = val;
    }
  }
  __syncthreads();
  if (tid < BM_) {
    float s = 0.f;
#pragma unroll
    for (int ww = 0; ww < 8; ww++) s += pe[ww][tid];
    e_out[(size_t)(R0 + tid)] = s;
  }
}

// ---------------------------------------------------------------------------
// Kernel D: softmax over L per batch.
// ---------------------------------------------------------------------------
__global__ __launch_bounds__(256) void k_softmax(const float* __restrict__ e,
                                                 float* __restrict__ w) {
  __shared__ float sh[L_];
  __shared__ float red[4];
  const int b = blockIdx.x, tid = threadIdx.x;
  const int lane = tid & 63, wv = tid >> 6;

  float m = -1e30f;
  for (int idx = tid; idx < L_; idx += 256) {
    float t = e[(size_t)b * L_ + idx];
    sh[idx] = t;
    m = fmaxf(m, t);
  }
  m = fmaxf(m, __shfl_down(m, 32));
  m = fmaxf(m, __shfl_down(m, 16));
  m = fmaxf(m, __shfl_down(m, 8));
  m = fmaxf(m, __shfl_down(m, 4));
  m = fmaxf(m, __shfl_down(m, 2));
  m = fmaxf(m, __shfl_down(m, 1));
  if (lane == 0) red[wv] = m;
  __syncthreads();
  m = fmaxf(fmaxf(red[0], red[1]), fmaxf(red[2], red[3]));
  __syncthreads();

  float s = 0.f;
  for (int idx = tid; idx < L_; idx += 256) {
    float t = expf(sh[idx] - m);
    sh[idx] = t;
    s += t;
  }
  s += __shfl_down(s, 32);
  s += __shfl_down(s, 16);
  s += __shfl_down(s, 8);
  s += __shfl_down(s, 4);
  s += __shfl_down(s, 2);
  s += __shfl_down(s, 1);
  if (lane == 0) red[wv] = s;
  __syncthreads();
  float total = red[0] + red[1] + red[2] + red[3];
  float inv = 1.f / total;
  for (int idx = tid; idx < L_; idx += 256)
    w[(size_t)b * L_ + idx] = sh[idx] * inv;
}

// ---------------------------------------------------------------------------
// Kernel E: context c_At[b][c] = sum_l w[b][l] * i[b][c][l]  (memory-bound)
// ---------------------------------------------------------------------------
__global__ __launch_bounds__(256) void k_context(const float* __restrict__ i_,
                                                 const float* __restrict__ w,
                                                 float* __restrict__ out) {
  __shared__ float red[4];
  const int b = blockIdx.y, c = blockIdx.x, tid = threadIdx.x;
  const int lane = tid & 63, wv = tid >> 6;
  const float4* row = (const float4*)(i_ + ((size_t)b * C_ + c) * L_);
  const float4* wr  = (const float4*)(w + (size_t)b * L_);
  float s = 0.f;
  for (int idx = tid; idx < L_ / 4; idx += 256) {
    float4 a = row[idx];
    float4 ww = wr[idx];
    s += a.x * ww.x + a.y * ww.y + a.z * ww.z + a.w * ww.w;
  }
  s += __shfl_down(s, 32);
  s += __shfl_down(s, 16);
  s += __shfl_down(s, 8);
  s += __shfl_down(s, 4);
  s += __shfl_down(s, 2);
  s += __shfl_down(s, 1);
  if (lane == 0) red[wv] = s;
  __syncthreads();
  if (tid == 0) out[(size_t)b * C_ + c] = red[0] + red[1] + red[2] + red[3];
}

// ---------------------------------------------------------------------------
extern "C" void kernel_launch(void* const* d_in, const int* in_sizes, int n_in,
                              void* d_out, int out_size, void* d_ws, size_t ws_size,
                              hipStream_t stream) {
  const float* i_      = (const float*)d_in[0];
  const float* hat_s_t = (const float*)d_in[1];
  const float* alpha   = (const float*)d_in[2];
  const float* conv_w  = (const float*)d_in[3];
  const float* conv_b  = (const float*)d_in[4];
  const float* Wa      = (const float*)d_in[5];
  const float* Wf      = (const float*)d_in[6];
  const float* Ws      = (const float*)d_in[7];
  const float* v       = (const float*)d_in[8];
  float* out = (float*)d_out;

  float* ws   = (float*)d_ws;
  float* hsb  = ws;                               // 32*512    f
  float* w2   = hsb + B_ * NP_;                   // 121*512   f
  float* e    = w2 + KK_ * NP_;                   // 32*3136   f
  float* anew = e + B_ * L_;                      // 32*3136   f
  unsigned short* Wbp = (unsigned short*)(anew + B_ * L_);  // 16*52*1024 u16 = 1.7 MB
  // total ~2.8 MB workspace

  k_hsb<<<dim3(B_), dim3(256), 0, stream>>>(hat_s_t, Ws, conv_b, Wf, hsb);
  k_w2<<<dim3(KK_), dim3(256), 0, stream>>>(conv_w, Wf, w2);
  k_wb<<<dim3(KT_), dim3(512), 0, stream>>>(Wa, w2, Wbp);
  k_energy<<<dim3((B_ * L_) / BM_), dim3(512), 0, stream>>>(i_, alpha, Wbp, hsb, v, e);
  k_softmax<<<dim3(B_), dim3(256), 0, stream>>>(e, anew);
  k_context<<<dim3(C_, B_), dim3(256), 0, stream>>>(i_, anew, out);
}